// Round 7
// baseline (918.765 us; speedup 1.0000x reference)
//
#include <hip/hip_runtime.h>
#include <hip/hip_bf16.h>
#include <math.h>

typedef __hip_bfloat16 bf16;
typedef __bf16 bf16x8 __attribute__((ext_vector_type(8)));
typedef float  f32x4  __attribute__((ext_vector_type(4)));

#define BB 8
#define CC 96
#define HH 224
#define WW 224
#define HWPIX (HH*WW)
#define TOK 49          // 7*7 tokens per window
#define NWIN 1024       // windows per image
#define NTOK (BB*HH*WW) // 401408 tokens

// bf16 weight cache layout in workspace tail (elements):
//   qkv @ 0 (27648) | proj @ 27648 (9216) | w1 @ 36864 (36864) | w2 @ 73728 (36864)
#define WTAIL_BYTES 221184

// convert 8 consecutive f32 -> bf16x8 fragment
__device__ __forceinline__ bf16x8 cvt8(const float* __restrict__ p) {
    f32x4 a = *(const f32x4*)p;
    f32x4 c = *(const f32x4*)(p + 4);
    bf16x8 r;
    r[0] = (__bf16)a[0]; r[1] = (__bf16)a[1]; r[2] = (__bf16)a[2]; r[3] = (__bf16)a[3];
    r[4] = (__bf16)c[0]; r[5] = (__bf16)c[1]; r[6] = (__bf16)c[2]; r[7] = (__bf16)c[3];
    return r;
}

// load a B-fragment row-slice: direct bf16 if cache available, else f32+cvt
__device__ __forceinline__ bf16x8 ldw8(const float* __restrict__ wf,
                                       const __bf16* __restrict__ wb, int off) {
    if (wb) return *(const bf16x8*)(wb + off);
    return cvt8(wf + off);
}

// load 8 consecutive channels c0..c0+7 of a token (vector when channels
// contiguous, scalar gather otherwise)
__device__ __forceinline__ void load8(const float* __restrict__ p, int base,
                                      int c0, int sC, float* __restrict__ dst) {
    if (sC == 1) {
        f32x4 x = *(const f32x4*)(p + base + c0);
        f32x4 y = *(const f32x4*)(p + base + c0 + 4);
        dst[0]=x[0]; dst[1]=x[1]; dst[2]=x[2]; dst[3]=x[3];
        dst[4]=y[0]; dst[5]=y[1]; dst[6]=y[2]; dst[7]=y[3];
    } else {
        #pragma unroll
        for (int j = 0; j < 8; ++j) dst[j] = p[base + (c0 + j) * sC];
    }
}

// ---------------- f32 -> bf16 weight conversion (one-shot) ----------------
__global__ __launch_bounds__(256) void k_cvt(const float* __restrict__ src,
                                             __bf16* __restrict__ dst, int n8) {
    int i = blockIdx.x * 256 + threadIdx.x;
    if (i < n8) *(bf16x8*)(dst + i*8) = cvt8(src + i*8);
}

// ---------------- tiled transpose: NCHW -> NHWC (float4 both sides) -------
__global__ __launch_bounds__(256) void k_nchw2nhwc(const float* __restrict__ x,
                                                   float* __restrict__ hbuf) {
    __shared__ float tile[CC][57];  // 56-wide w tile, +1 pad
    int bid = blockIdx.x;
    int wc = bid & 3;           // 4 chunks of 56 along W
    int bh = bid >> 2;
    int h = bh % HH;
    int b = bh / HH;
    int w0 = wc * 56;
    for (int i = threadIdx.x; i < CC*14; i += 256) {
        int c = i / 14, w4 = (i % 14) * 4;
        f32x4 v = *(const f32x4*)&x[((b*CC + c)*HH + h)*WW + w0 + w4];
        tile[c][w4+0] = v[0]; tile[c][w4+1] = v[1];
        tile[c][w4+2] = v[2]; tile[c][w4+3] = v[3];
    }
    __syncthreads();
    for (int i = threadIdx.x; i < 56*24; i += 256) {
        int w = i / 24, c4 = (i % 24) * 4;
        f32x4 v;
        v[0] = tile[c4+0][w]; v[1] = tile[c4+1][w];
        v[2] = tile[c4+2][w]; v[3] = tile[c4+3][w];
        *(f32x4*)&hbuf[((b*HH + h)*WW + w0 + w)*CC + c4] = v;
    }
}

// ---------------- Kernel A: shifted-window attention + residual (MFMA) ----
// one block (256 thr, 4 waves) per window; 8192 blocks.
// Tokens padded 49->64 (M=64).
// MFMA fragment layouts (verified): A[m=lane&15][k=quad*8+j],
// B^T[n=lane&15][k=quad*8+j], C/D col=lane&15, row=quad*4+reg.
// LN1 fused into QKV (register LN via quad-shuffle); O overwrites kss.
// Weights loaded as bf16 from cache when available (no cvt chains).
// LDS = 40,448 B -> 4 blocks/CU by LDS. 3 barriers.
__global__ __launch_bounds__(256) void k_attn(const float* __restrict__ inbuf,
                                              float* __restrict__ outbuf,
                                              const float* __restrict__ n1w,
                                              const float* __restrict__ n1b,
                                              const float* __restrict__ qkv_w,
                                              const float* __restrict__ qkv_b,
                                              const float* __restrict__ rel_table,
                                              const float* __restrict__ proj_w,
                                              const float* __restrict__ proj_b,
                                              const __bf16* __restrict__ qkv_wb,
                                              const __bf16* __restrict__ proj_wb,
                                              int sB, int sH, int sW, int sC) {
    // stride 104 bf16 = 208B = 52 dw: rowm*52 % 32 cycles 8 banks -> 2-way (free)
    __shared__ __attribute__((aligned(16))) __bf16 qs [64][104]; // Q*scale, later P (softmax)
    __shared__ __attribute__((aligned(16))) __bf16 kss[64][104]; // K, later O (PV result)
    __shared__ __attribute__((aligned(16))) __bf16 vsT[96][72];  // V transposed [c][t]

    const int tid  = threadIdx.x;
    const int lane = tid & 63;
    const int wv   = tid >> 6;
    const int rowm = lane & 15;
    const int quad = lane >> 4;
    const int mi   = wv >> 1;   // 0..1: row half for 2x2-tiled phases
    const int ni   = wv & 1;    // 0..1: col half

    const int gi = blockIdx.x;
    const int b  = gi >> 10;
    const int wrem = gi & 1023;
    const int wy = wrem >> 5;
    const int wx = wrem & 31;

    // ---- phase 1: fused LN1 (in-register) + QKV MFMA -> qs/kss/vsT ----
    bf16x8 afrag[2][3];
    #pragma unroll
    for (int mt = 0; mt < 2; ++mt) {
        const int tk = (2*mi + mt)*16 + rowm;
        const bool valid = (tk < TOK);
        float v[24];
        if (valid) {
            int ty = tk / 7, tx = tk - 7*ty;
            int hr = wy*7 + ty, wr = wx*7 + tx;
            int sh = hr + 3; if (sh >= HH) sh -= HH;
            int sw = wr + 3; if (sw >= WW) sw -= WW;
            int base = b*sB + sh*sH + sw*sW;
            #pragma unroll
            for (int ks = 0; ks < 3; ++ks)
                load8(inbuf, base, ks*32 + quad*8, sC, v + ks*8);
        } else {
            #pragma unroll
            for (int j = 0; j < 24; ++j) v[j] = 0.f;
        }
        float s = 0.f, s2 = 0.f;
        #pragma unroll
        for (int j = 0; j < 24; ++j) { s += v[j]; s2 += v[j]*v[j]; }
        s  += __shfl_xor(s,  16, 64);  s2 += __shfl_xor(s2, 16, 64);
        s  += __shfl_xor(s,  32, 64);  s2 += __shfl_xor(s2, 32, 64);
        float mu  = s * (1.f/96.f);
        float var = s2 * (1.f/96.f) - mu*mu;
        float rs  = rsqrtf(var + 1e-5f);
        #pragma unroll
        for (int ks = 0; ks < 3; ++ks) {
            int c0 = ks*32 + quad*8;
            f32x4 w0 = *(const f32x4*)(n1w + c0);
            f32x4 w1 = *(const f32x4*)(n1w + c0 + 4);
            f32x4 b0 = *(const f32x4*)(n1b + c0);
            f32x4 b1 = *(const f32x4*)(n1b + c0 + 4);
            bf16x8 f;
            f[0] = (__bf16)(valid ? (v[ks*8+0]-mu)*rs*w0[0]+b0[0] : 0.f);
            f[1] = (__bf16)(valid ? (v[ks*8+1]-mu)*rs*w0[1]+b0[1] : 0.f);
            f[2] = (__bf16)(valid ? (v[ks*8+2]-mu)*rs*w0[2]+b0[2] : 0.f);
            f[3] = (__bf16)(valid ? (v[ks*8+3]-mu)*rs*w0[3]+b0[3] : 0.f);
            f[4] = (__bf16)(valid ? (v[ks*8+4]-mu)*rs*w1[0]+b1[0] : 0.f);
            f[5] = (__bf16)(valid ? (v[ks*8+5]-mu)*rs*w1[1]+b1[1] : 0.f);
            f[6] = (__bf16)(valid ? (v[ks*8+6]-mu)*rs*w1[2]+b1[2] : 0.f);
            f[7] = (__bf16)(valid ? (v[ks*8+7]-mu)*rs*w1[3]+b1[3] : 0.f);
            afrag[mt][ks] = f;
        }
    }
    {
        const float qscale = 0.10206207261596577f; // 96^-0.5
        #pragma unroll 3
        for (int nt = 0; nt < 9; ++nt) {
            int j = ni*144 + nt*16 + rowm;          // output column (0..287)
            int wo = j*CC + quad*8;
            bf16x8 b0 = ldw8(qkv_w, qkv_wb, wo);
            bf16x8 b1 = ldw8(qkv_w, qkv_wb, wo + 32);
            bf16x8 b2 = ldw8(qkv_w, qkv_wb, wo + 64);
            float bias = qkv_b[j];
            #pragma unroll
            for (int mt = 0; mt < 2; ++mt) {
                f32x4 acc = (f32x4){0.f,0.f,0.f,0.f};
                acc = __builtin_amdgcn_mfma_f32_16x16x32_bf16(afrag[mt][0], b0, acc, 0,0,0);
                acc = __builtin_amdgcn_mfma_f32_16x16x32_bf16(afrag[mt][1], b1, acc, 0,0,0);
                acc = __builtin_amdgcn_mfma_f32_16x16x32_bf16(afrag[mt][2], b2, acc, 0,0,0);
                #pragma unroll
                for (int r = 0; r < 4; ++r) {
                    int tok = (2*mi+mt)*16 + quad*4 + r;
                    float val = acc[r] + bias;
                    if (j < 96)        qs [tok][j]      = (__bf16)(val * qscale);
                    else if (j < 192)  kss[tok][j-96]   = (__bf16)val;
                    else               vsT[j-192][tok]  = (__bf16)val;
                }
            }
        }
    }
    __syncthreads();

    // ---- phase 2: S = Q@K^T + rel_bias + mask; IN-REGISTER softmax; P->qs --
    {
        bf16x8 a0 = *(const bf16x8*)&qs[16*wv + rowm][ 0 + quad*8];
        bf16x8 a1 = *(const bf16x8*)&qs[16*wv + rowm][32 + quad*8];
        bf16x8 a2 = *(const bf16x8*)&qs[16*wv + rowm][64 + quad*8];
        f32x4 acc[4];
        int ky[4], kx[4];
        #pragma unroll
        for (int nt = 0; nt < 4; ++nt) {
            bf16x8 b0 = *(const bf16x8*)&kss[nt*16 + rowm][ 0 + quad*8];
            bf16x8 b1 = *(const bf16x8*)&kss[nt*16 + rowm][32 + quad*8];
            bf16x8 b2 = *(const bf16x8*)&kss[nt*16 + rowm][64 + quad*8];
            f32x4 t = (f32x4){0.f,0.f,0.f,0.f};
            t = __builtin_amdgcn_mfma_f32_16x16x32_bf16(a0, b0, t, 0,0,0);
            t = __builtin_amdgcn_mfma_f32_16x16x32_bf16(a1, b1, t, 0,0,0);
            t = __builtin_amdgcn_mfma_f32_16x16x32_bf16(a2, b2, t, 0,0,0);
            acc[nt] = t;
            int kt = nt*16 + rowm;
            ky[nt] = kt / 7; kx[nt] = kt - 7*ky[nt];
        }
        const bool eY = (wy == 31), eX = (wx == 31);
        #pragma unroll
        for (int r = 0; r < 4; ++r) {
            int qt = 16*wv + quad*4 + r;
            int qy = qt / 7, qx = qt - 7*qy;
            int lq = (eY ? (qy < 4 ? 3 : 6) : 0) + (eX ? (qx < 4 ? 1 : 2) : 0);
            float sv[4];
            #pragma unroll
            for (int nt = 0; nt < 4; ++nt) {
                int kt = nt*16 + rowm;
                float v = acc[nt][r];
                if (kt < TOK && qt < TOK) {
                    v += rel_table[(qy - ky[nt] + 6)*13 + (qx - kx[nt] + 6)];
                    if (eY || eX) {
                        int lk = (eY ? (ky[nt] < 4 ? 3 : 6) : 0)
                               + (eX ? (kx[nt] < 4 ? 1 : 2) : 0);
                        if (lq != lk) v -= 100.f;
                    }
                } else v = -3.0e38f;
                sv[nt] = v;
            }
            float m = fmaxf(fmaxf(sv[0], sv[1]), fmaxf(sv[2], sv[3]));
            #pragma unroll
            for (int off = 8; off; off >>= 1)
                m = fmaxf(m, __shfl_xor(m, off, 64));
            float e0 = __expf(sv[0]-m), e1 = __expf(sv[1]-m);
            float e2 = __expf(sv[2]-m), e3 = __expf(sv[3]-m);
            float s = (e0+e1)+(e2+e3);
            #pragma unroll
            for (int off = 8; off; off >>= 1)
                s += __shfl_xor(s, off, 64);
            float inv = 1.f / s;
            qs[qt][ 0 + rowm] = (__bf16)(e0*inv);
            qs[qt][16 + rowm] = (__bf16)(e1*inv);
            qs[qt][32 + rowm] = (__bf16)(e2*inv);
            qs[qt][48 + rowm] = (__bf16)(e3*inv);
        }
    }
    __syncthreads();

    // ---- phase 3: O = P @ V, MFMA; O -> kss (K dead) ----
    {
        bf16x8 a[2][2];
        #pragma unroll
        for (int mt = 0; mt < 2; ++mt)
            #pragma unroll
            for (int ku = 0; ku < 2; ++ku)
                a[mt][ku] = *(const bf16x8*)&qs[(2*mi+mt)*16 + rowm][ku*32 + quad*8];

        #pragma unroll
        for (int nt = 0; nt < 3; ++nt) {
            int c = ni*48 + nt*16 + rowm;
            bf16x8 b0 = *(const bf16x8*)&vsT[c][ 0 + quad*8];
            bf16x8 b1 = *(const bf16x8*)&vsT[c][32 + quad*8];
            #pragma unroll
            for (int mt = 0; mt < 2; ++mt) {
                f32x4 acc = (f32x4){0.f,0.f,0.f,0.f};
                acc = __builtin_amdgcn_mfma_f32_16x16x32_bf16(a[mt][0], b0, acc, 0,0,0);
                acc = __builtin_amdgcn_mfma_f32_16x16x32_bf16(a[mt][1], b1, acc, 0,0,0);
                #pragma unroll
                for (int r = 0; r < 4; ++r)
                    kss[(2*mi+mt)*16 + quad*4 + r][c] = (__bf16)acc[r];
            }
        }
    }
    __syncthreads();

    // ---- phase 4: out = O @ proj_w^T + bias + residual (addresses inline) --
    {
        bf16x8 a[2][3];
        #pragma unroll
        for (int mt = 0; mt < 2; ++mt)
            #pragma unroll
            for (int ks = 0; ks < 3; ++ks)
                a[mt][ks] = *(const bf16x8*)&kss[(2*mi+mt)*16 + rowm][ks*32 + quad*8];

        int obase[2][4];
        #pragma unroll
        for (int mt = 0; mt < 2; ++mt)
            #pragma unroll
            for (int r = 0; r < 4; ++r) {
                int tok = (2*mi+mt)*16 + quad*4 + r;
                if (tok < TOK) {
                    int ty = tok / 7, tx = tok - 7*ty;
                    int hr = wy*7 + ty, wr2 = wx*7 + tx;
                    int sh = hr + 3; if (sh >= HH) sh -= HH;
                    int sw = wr2 + 3; if (sw >= WW) sw -= WW;
                    obase[mt][r] = b*sB + sh*sH + sw*sW;
                } else obase[mt][r] = -1;
            }

        #pragma unroll
        for (int nt = 0; nt < 3; ++nt) {
            int c = ni*48 + nt*16 + rowm;
            int wo = c*CC + quad*8;
            bf16x8 b0 = ldw8(proj_w, proj_wb, wo);
            bf16x8 b1 = ldw8(proj_w, proj_wb, wo + 32);
            bf16x8 b2 = ldw8(proj_w, proj_wb, wo + 64);
            float bias = proj_b[c];
            #pragma unroll
            for (int mt = 0; mt < 2; ++mt) {
                f32x4 acc = (f32x4){0.f,0.f,0.f,0.f};
                acc = __builtin_amdgcn_mfma_f32_16x16x32_bf16(a[mt][0], b0, acc, 0,0,0);
                acc = __builtin_amdgcn_mfma_f32_16x16x32_bf16(a[mt][1], b1, acc, 0,0,0);
                acc = __builtin_amdgcn_mfma_f32_16x16x32_bf16(a[mt][2], b2, acc, 0,0,0);
                #pragma unroll
                for (int r = 0; r < 4; ++r) {
                    if (obase[mt][r] >= 0) {
                        int g = obase[mt][r] + c*sC;
                        outbuf[g] = inbuf[g] + acc[r] + bias;
                    }
                }
            }
        }
    }
}

// ---------------- Kernel B (fast path): LN2 + MLP + residual, MFMA --------
// Register-fused LN2; B-fragments loaded DIRECTLY from global (L1/L2-hot,
// no LDS staging, zero barriers in the chunk loop). sH wave-private.
// NCHW write-out fused via sOut overlay (2 barriers total).
// LDS = 24,832 B -> 6 blocks/CU.
__global__ __launch_bounds__(256) void k_mlp_mfma(const float* __restrict__ buf,
                                                  float* __restrict__ out,
                                                  const float* __restrict__ n2w,
                                                  const float* __restrict__ n2b,
                                                  const float* __restrict__ w1g,
                                                  const float* __restrict__ b1g,
                                                  const float* __restrict__ w2g,
                                                  const float* __restrict__ b2g,
                                                  const __bf16* __restrict__ w1b,
                                                  const __bf16* __restrict__ w2b) {
    // sH [64][72] bf16 @0 (9216) ; epilogue overlay sOut [64][97] f32 @0 (24832)
    __shared__ __attribute__((aligned(16))) char smraw[24832];
    auto sH   = (__bf16(*)[72])(smraw);
    auto sOut = (float(*)[97])(smraw);

    const int tid  = threadIdx.x;
    const int lane = tid & 63;
    const int wv   = tid >> 6;
    const int rowm = lane & 15;
    const int quad = lane >> 4;
    const int t0   = blockIdx.x * 64;

    // ---- fused LN2 in registers: lane owns token 16wv+rowm, chans ks*32+quad*8
    bf16x8 afrag[3];
    {
        const int base = (t0 + 16*wv + rowm) * CC;
        float v[24];
        #pragma unroll
        for (int ks = 0; ks < 3; ++ks) {
            f32x4 x = *(const f32x4*)(buf + base + ks*32 + quad*8);
            f32x4 y = *(const f32x4*)(buf + base + ks*32 + quad*8 + 4);
            v[ks*8+0]=x[0]; v[ks*8+1]=x[1]; v[ks*8+2]=x[2]; v[ks*8+3]=x[3];
            v[ks*8+4]=y[0]; v[ks*8+5]=y[1]; v[ks*8+6]=y[2]; v[ks*8+7]=y[3];
        }
        float s = 0.f, s2 = 0.f;
        #pragma unroll
        for (int j = 0; j < 24; ++j) { s += v[j]; s2 += v[j]*v[j]; }
        s  += __shfl_xor(s,  16, 64);  s2 += __shfl_xor(s2, 16, 64);
        s  += __shfl_xor(s,  32, 64);  s2 += __shfl_xor(s2, 32, 64);
        float mu  = s * (1.f/96.f);
        float var = s2 * (1.f/96.f) - mu*mu;
        float rs  = rsqrtf(var + 1e-5f);
        #pragma unroll
        for (int ks = 0; ks < 3; ++ks) {
            int c0 = ks*32 + quad*8;
            f32x4 w0 = *(const f32x4*)(n2w + c0);
            f32x4 w1 = *(const f32x4*)(n2w + c0 + 4);
            f32x4 b0 = *(const f32x4*)(n2b + c0);
            f32x4 b1 = *(const f32x4*)(n2b + c0 + 4);
            bf16x8 f;
            f[0] = (__bf16)((v[ks*8+0]-mu)*rs*w0[0]+b0[0]);
            f[1] = (__bf16)((v[ks*8+1]-mu)*rs*w0[1]+b0[1]);
            f[2] = (__bf16)((v[ks*8+2]-mu)*rs*w0[2]+b0[2]);
            f[3] = (__bf16)((v[ks*8+3]-mu)*rs*w0[3]+b0[3]);
            f[4] = (__bf16)((v[ks*8+4]-mu)*rs*w1[0]+b1[0]);
            f[5] = (__bf16)((v[ks*8+5]-mu)*rs*w1[1]+b1[1]);
            f[6] = (__bf16)((v[ks*8+6]-mu)*rs*w1[2]+b1[2]);
            f[7] = (__bf16)((v[ks*8+7]-mu)*rs*w1[3]+b1[3]);
            afrag[ks] = f;
        }
    }

    f32x4 acc2[6];
    #pragma unroll
    for (int nt = 0; nt < 6; ++nt) acc2[nt] = (f32x4){0.f,0.f,0.f,0.f};

    for (int ch = 0; ch < 6; ++ch) {
        // GEMM1 + GELU -> sH (wave-private rows; B direct from global)
        #pragma unroll
        for (int nt = 0; nt < 4; ++nt) {
            int row = ch*64 + nt*16 + rowm;           // W1 row (hidden unit)
            int wo = row*96 + quad*8;
            bf16x8 w0  = ldw8(w1g, w1b, wo);
            bf16x8 w1v = ldw8(w1g, w1b, wo + 32);
            bf16x8 w2v = ldw8(w1g, w1b, wo + 64);
            f32x4 acc = (f32x4){0.f,0.f,0.f,0.f};
            acc = __builtin_amdgcn_mfma_f32_16x16x32_bf16(afrag[0], w0,  acc, 0,0,0);
            acc = __builtin_amdgcn_mfma_f32_16x16x32_bf16(afrag[1], w1v, acc, 0,0,0);
            acc = __builtin_amdgcn_mfma_f32_16x16x32_bf16(afrag[2], w2v, acc, 0,0,0);
            float bias = b1g[row];
            #pragma unroll
            for (int r = 0; r < 4; ++r) {
                float v = acc[r] + bias;
                v = 0.5f * v * (1.f + erff(v * 0.70710678118654752f));
                sH[16*wv + quad*4 + r][nt*16 + rowm] = (__bf16)v;
            }
        }

        // GEMM2 partial: reads sH rows this wave just wrote (lgkmcnt-ordered)
        bf16x8 h0 = *(const bf16x8*)&sH[16*wv + rowm][ 0 + quad*8];
        bf16x8 h1 = *(const bf16x8*)&sH[16*wv + rowm][32 + quad*8];
        #pragma unroll
        for (int nt = 0; nt < 6; ++nt) {
            int row = nt*16 + rowm;                    // W2 row (output channel)
            int wo = row*384 + ch*64 + quad*8;
            bf16x8 w0  = ldw8(w2g, w2b, wo);
            bf16x8 w1v = ldw8(w2g, w2b, wo + 32);
            acc2[nt] = __builtin_amdgcn_mfma_f32_16x16x32_bf16(h0, w0,  acc2[nt], 0,0,0);
            acc2[nt] = __builtin_amdgcn_mfma_f32_16x16x32_bf16(h1, w1v, acc2[nt], 0,0,0);
        }
    }

    // ---- epilogue: + b2 + residual -> sOut (overlays sH), then NCHW store --
    __syncthreads();   // all waves done with sH before overlay write
    #pragma unroll
    for (int nt = 0; nt < 6; ++nt) {
        int c = nt*16 + rowm;
        float bias = b2g[c];
        #pragma unroll
        for (int r = 0; r < 4; ++r) {
            int t = 16*wv + quad*4 + r;
            sOut[t][c] = buf[(t0 + t)*CC + c] + acc2[nt][r] + bias;
        }
    }
    __syncthreads();
    {
        int b  = t0 / HWPIX;           // 64-token blocks never straddle b
        int p0 = t0 - b*HWPIX;
        for (int i = tid; i < CC*64; i += 256) {
            int c = i >> 6, t = i & 63;
            out[(b*CC + c)*HWPIX + p0 + t] = sOut[t][c];
        }
    }
}

// ---------------- Kernel B (fallback, strided scalar) ----------------------
__global__ __launch_bounds__(256) void k_mlp_s(float* __restrict__ buf,
                                               const float* __restrict__ n2w,
                                               const float* __restrict__ n2b,
                                               const float* __restrict__ w1,
                                               const float* __restrict__ b1,
                                               const float* __restrict__ w2,
                                               const float* __restrict__ b2,
                                               int sB, int sPix, int sC) {
    __shared__ float ln2[4][CC];
    __shared__ float hid[4][384];
    __shared__ float hraw[4][CC];
    __shared__ int   tbase[4];

    const int tid  = threadIdx.x;
    const int lane = tid & 63;
    const int wv   = tid >> 6;
    const int tok0 = blockIdx.x * 4;

    {
        int tok = tok0 + wv;
        int base = (tok / HWPIX)*sB + (tok % HWPIX)*sPix;
        if (lane == 0) tbase[wv] = base;
        float v0 = buf[base + lane*sC];
        float v1 = (lane < 32) ? buf[base + (64 + lane)*sC] : 0.f;
        float s  = v0 + v1;
        float s2 = v0*v0 + v1*v1;
        #pragma unroll
        for (int off = 32; off; off >>= 1) {
            s  += __shfl_down(s,  off, 64);
            s2 += __shfl_down(s2, off, 64);
        }
        s  = __shfl(s, 0, 64);
        s2 = __shfl(s2, 0, 64);
        float mu  = s * (1.f/96.f);
        float var = s2 * (1.f/96.f) - mu*mu;
        float rs  = rsqrtf(var + 1e-5f);
        hraw[wv][lane] = v0;
        ln2[wv][lane]  = (v0 - mu)*rs*n2w[lane] + n2b[lane];
        if (lane < 32) {
            hraw[wv][64+lane] = v1;
            ln2[wv][64+lane]  = (v1 - mu)*rs*n2w[64+lane] + n2b[64+lane];
        }
    }
    __syncthreads();

    for (int o = tid; o < 4*384; o += 256) {
        int ti = o / 384, j = o % 384;
        const float* wrow = w1 + j*CC;
        float acc = b1[j];
        #pragma unroll 8
        for (int c = 0; c < CC; ++c) acc += ln2[ti][c] * wrow[c];
        hid[ti][j] = 0.5f * acc * (1.f + erff(acc * 0.70710678118654752f));
    }
    __syncthreads();

    for (int o = tid; o < 4*CC; o += 256) {
        int ti = o / CC, c = o % CC;
        const float* wrow = w2 + c*384;
        float acc = b2[c];
        #pragma unroll 8
        for (int k = 0; k < 384; ++k) acc += hid[ti][k] * wrow[k];
        buf[tbase[ti] + c*sC] = hraw[ti][c] + acc;
    }
}

extern "C" void kernel_launch(void* const* d_in, const int* in_sizes, int n_in,
                              void* d_out, int out_size, void* d_ws, size_t ws_size,
                              hipStream_t stream) {
    const float* x        = (const float*)d_in[0];
    const float* norm1_w  = (const float*)d_in[1];
    const float* norm1_b  = (const float*)d_in[2];
    const float* qkv_w    = (const float*)d_in[3];
    const float* qkv_b    = (const float*)d_in[4];
    const float* rel_tab  = (const float*)d_in[5];
    const float* proj_w   = (const float*)d_in[6];
    const float* proj_b   = (const float*)d_in[7];
    const float* norm2_w  = (const float*)d_in[8];
    const float* norm2_b  = (const float*)d_in[9];
    const float* mlp_w1   = (const float*)d_in[10];
    const float* mlp_b1   = (const float*)d_in[11];
    const float* mlp_w2   = (const float*)d_in[12];
    const float* mlp_b2   = (const float*)d_in[13];
    float* out = (float*)d_out;

    const int n = BB*CC*HH*WW;
    const size_t need = (size_t)n * sizeof(float); // 154,140,672 B

    dim3 blk(256);
    if (ws_size >= need) {
        float* hbuf = (float*)d_ws;
        __bf16* qkv_wb = nullptr; __bf16* proj_wb = nullptr;
        __bf16* w1b = nullptr;    __bf16* w2b = nullptr;
        if (ws_size >= need + WTAIL_BYTES) {
            __bf16* wt = (__bf16*)((char*)d_ws + need);
            qkv_wb  = wt;
            proj_wb = wt + 27648;
            w1b     = wt + 36864;
            w2b     = wt + 73728;
            k_cvt<<<dim3((27648/8+255)/256), blk, 0, stream>>>(qkv_w,  qkv_wb,  27648/8);
            k_cvt<<<dim3(( 9216/8+255)/256), blk, 0, stream>>>(proj_w, proj_wb,  9216/8);
            k_cvt<<<dim3((36864/8+255)/256), blk, 0, stream>>>(mlp_w1, w1b,     36864/8);
            k_cvt<<<dim3((36864/8+255)/256), blk, 0, stream>>>(mlp_w2, w2b,     36864/8);
        }
        k_nchw2nhwc<<<dim3(BB*HH*4), blk, 0, stream>>>(x, hbuf);
        k_attn<<<dim3(BB*NWIN), blk, 0, stream>>>(hbuf, hbuf,
                norm1_w, norm1_b, qkv_w, qkv_b, rel_tab, proj_w, proj_b,
                qkv_wb, proj_wb,
                HH*WW*CC, WW*CC, CC, 1);
        k_mlp_mfma<<<dim3(NTOK/64), blk, 0, stream>>>(hbuf, out,
                norm2_w, norm2_b, mlp_w1, mlp_b1, mlp_w2, mlp_b2, w1b, w2b);
    } else {
        k_attn<<<dim3(BB*NWIN), blk, 0, stream>>>(x, out,
                norm1_w, norm1_b, qkv_w, qkv_b, rel_tab, proj_w, proj_b,
                nullptr, nullptr,
                CC*HH*WW, WW, 1, HH*WW);
        k_mlp_s<<<dim3(NTOK/4), blk, 0, stream>>>(out,
                norm2_w, norm2_b, mlp_w1, mlp_b1, mlp_w2, mlp_b2,
                CC*HH*WW, 1, HH*WW);
    }
}

// Round 8
// 787.230 us; speedup vs baseline: 1.1671x; 1.1671x over previous
//
#include <hip/hip_runtime.h>
#include <hip/hip_bf16.h>
#include <math.h>

typedef __hip_bfloat16 bf16;
typedef __bf16 bf16x8 __attribute__((ext_vector_type(8)));
typedef float  f32x4  __attribute__((ext_vector_type(4)));

#define BB 8
#define CC 96
#define HH 224
#define WW 224
#define HWPIX (HH*WW)
#define TOK 49          // 7*7 tokens per window
#define NWIN 1024       // windows per image
#define NTOK (BB*HH*WW) // 401408 tokens

// bf16 weight cache layout in workspace tail (elements):
//   qkv @ 0 (27648) | proj @ 27648 (9216) | w1 @ 36864 (36864) | w2 @ 73728 (36864)
#define WTAIL_BYTES 221184

// convert 8 consecutive f32 -> bf16x8 fragment
__device__ __forceinline__ bf16x8 cvt8(const float* __restrict__ p) {
    f32x4 a = *(const f32x4*)p;
    f32x4 c = *(const f32x4*)(p + 4);
    bf16x8 r;
    r[0] = (__bf16)a[0]; r[1] = (__bf16)a[1]; r[2] = (__bf16)a[2]; r[3] = (__bf16)a[3];
    r[4] = (__bf16)c[0]; r[5] = (__bf16)c[1]; r[6] = (__bf16)c[2]; r[7] = (__bf16)c[3];
    return r;
}

// load a B-fragment row-slice: direct bf16 if cache available, else f32+cvt
__device__ __forceinline__ bf16x8 ldw8(const float* __restrict__ wf,
                                       const __bf16* __restrict__ wb, int off) {
    if (wb) return *(const bf16x8*)(wb + off);
    return cvt8(wf + off);
}

// load 8 consecutive channels c0..c0+7 of a token (vector when channels
// contiguous, scalar gather otherwise)
__device__ __forceinline__ void load8(const float* __restrict__ p, int base,
                                      int c0, int sC, float* __restrict__ dst) {
    if (sC == 1) {
        f32x4 x = *(const f32x4*)(p + base + c0);
        f32x4 y = *(const f32x4*)(p + base + c0 + 4);
        dst[0]=x[0]; dst[1]=x[1]; dst[2]=x[2]; dst[3]=x[3];
        dst[4]=y[0]; dst[5]=y[1]; dst[6]=y[2]; dst[7]=y[3];
    } else {
        #pragma unroll
        for (int j = 0; j < 8; ++j) dst[j] = p[base + (c0 + j) * sC];
    }
}

// ---------------- all weights f32 -> bf16, one launch ----------------------
// dst layout: [qkv 27648 | proj 9216 | w1 36864 | w2 36864] = 110592 elems
__global__ __launch_bounds__(256) void k_cvt_all(const float* __restrict__ qkv,
                                                 const float* __restrict__ proj,
                                                 const float* __restrict__ w1,
                                                 const float* __restrict__ w2,
                                                 __bf16* __restrict__ dst) {
    int i = blockIdx.x * 256 + threadIdx.x;   // 8-elem group index
    if (i >= 13824) return;
    int e = i * 8;
    const float* src; int off;
    if (e < 27648)      { src = qkv;  off = e; }
    else if (e < 36864) { src = proj; off = e - 27648; }
    else if (e < 73728) { src = w1;   off = e - 36864; }
    else                { src = w2;   off = e - 73728; }
    *(bf16x8*)(dst + e) = cvt8(src + off);
}

// ---------------- tiled transpose: NCHW -> NHWC (float4 both sides) -------
__global__ __launch_bounds__(256) void k_nchw2nhwc(const float* __restrict__ x,
                                                   float* __restrict__ hbuf) {
    __shared__ float tile[CC][57];  // 56-wide w tile, +1 pad
    int bid = blockIdx.x;
    int wc = bid & 3;           // 4 chunks of 56 along W
    int bh = bid >> 2;
    int h = bh % HH;
    int b = bh / HH;
    int w0 = wc * 56;
    for (int i = threadIdx.x; i < CC*14; i += 256) {
        int c = i / 14, w4 = (i % 14) * 4;
        f32x4 v = *(const f32x4*)&x[((b*CC + c)*HH + h)*WW + w0 + w4];
        tile[c][w4+0] = v[0]; tile[c][w4+1] = v[1];
        tile[c][w4+2] = v[2]; tile[c][w4+3] = v[3];
    }
    __syncthreads();
    for (int i = threadIdx.x; i < 56*24; i += 256) {
        int w = i / 24, c4 = (i % 24) * 4;
        f32x4 v;
        v[0] = tile[c4+0][w]; v[1] = tile[c4+1][w];
        v[2] = tile[c4+2][w]; v[3] = tile[c4+3][w];
        *(f32x4*)&hbuf[((b*HH + h)*WW + w0 + w)*CC + c4] = v;
    }
}

// ---------------- Kernel A: shifted-window attention + residual (MFMA) ----
// one block (256 thr, 4 waves) per window; 8192 blocks.
// Tokens padded 49->64 (M=64).
// MFMA fragment layouts (verified): A[m=lane&15][k=quad*8+j],
// B^T[n=lane&15][k=quad*8+j], C/D col=lane&15, row=quad*4+reg.
// LN1 fused into QKV (register LN via quad-shuffle); O overwrites kss.
// Weights loaded as bf16 from cache when available (no cvt chains).
// LDS = 40,448 B -> 4 blocks/CU by LDS. 3 barriers.
__global__ __launch_bounds__(256) void k_attn(const float* __restrict__ inbuf,
                                              float* __restrict__ outbuf,
                                              const float* __restrict__ n1w,
                                              const float* __restrict__ n1b,
                                              const float* __restrict__ qkv_w,
                                              const float* __restrict__ qkv_b,
                                              const float* __restrict__ rel_table,
                                              const float* __restrict__ proj_w,
                                              const float* __restrict__ proj_b,
                                              const __bf16* __restrict__ qkv_wb,
                                              const __bf16* __restrict__ proj_wb,
                                              int sB, int sH, int sW, int sC) {
    // stride 104 bf16 = 208B = 52 dw: rowm*52 % 32 cycles 8 banks -> 2-way (free)
    __shared__ __attribute__((aligned(16))) __bf16 qs [64][104]; // Q*scale, later P (softmax)
    __shared__ __attribute__((aligned(16))) __bf16 kss[64][104]; // K, later O (PV result)
    __shared__ __attribute__((aligned(16))) __bf16 vsT[96][72];  // V transposed [c][t]

    const int tid  = threadIdx.x;
    const int lane = tid & 63;
    const int wv   = tid >> 6;
    const int rowm = lane & 15;
    const int quad = lane >> 4;
    const int mi   = wv >> 1;   // 0..1: row half for 2x2-tiled phases
    const int ni   = wv & 1;    // 0..1: col half

    const int gi = blockIdx.x;
    const int b  = gi >> 10;
    const int wrem = gi & 1023;
    const int wy = wrem >> 5;
    const int wx = wrem & 31;

    // ---- phase 1: fused LN1 (in-register) + QKV MFMA -> qs/kss/vsT ----
    bf16x8 afrag[2][3];
    #pragma unroll
    for (int mt = 0; mt < 2; ++mt) {
        const int tk = (2*mi + mt)*16 + rowm;
        const bool valid = (tk < TOK);
        float v[24];
        if (valid) {
            int ty = tk / 7, tx = tk - 7*ty;
            int hr = wy*7 + ty, wr = wx*7 + tx;
            int sh = hr + 3; if (sh >= HH) sh -= HH;
            int sw = wr + 3; if (sw >= WW) sw -= WW;
            int base = b*sB + sh*sH + sw*sW;
            #pragma unroll
            for (int ks = 0; ks < 3; ++ks)
                load8(inbuf, base, ks*32 + quad*8, sC, v + ks*8);
        } else {
            #pragma unroll
            for (int j = 0; j < 24; ++j) v[j] = 0.f;
        }
        float s = 0.f, s2 = 0.f;
        #pragma unroll
        for (int j = 0; j < 24; ++j) { s += v[j]; s2 += v[j]*v[j]; }
        s  += __shfl_xor(s,  16, 64);  s2 += __shfl_xor(s2, 16, 64);
        s  += __shfl_xor(s,  32, 64);  s2 += __shfl_xor(s2, 32, 64);
        float mu  = s * (1.f/96.f);
        float var = s2 * (1.f/96.f) - mu*mu;
        float rs  = rsqrtf(var + 1e-5f);
        #pragma unroll
        for (int ks = 0; ks < 3; ++ks) {
            int c0 = ks*32 + quad*8;
            f32x4 w0 = *(const f32x4*)(n1w + c0);
            f32x4 w1 = *(const f32x4*)(n1w + c0 + 4);
            f32x4 b0 = *(const f32x4*)(n1b + c0);
            f32x4 b1 = *(const f32x4*)(n1b + c0 + 4);
            bf16x8 f;
            f[0] = (__bf16)(valid ? (v[ks*8+0]-mu)*rs*w0[0]+b0[0] : 0.f);
            f[1] = (__bf16)(valid ? (v[ks*8+1]-mu)*rs*w0[1]+b0[1] : 0.f);
            f[2] = (__bf16)(valid ? (v[ks*8+2]-mu)*rs*w0[2]+b0[2] : 0.f);
            f[3] = (__bf16)(valid ? (v[ks*8+3]-mu)*rs*w0[3]+b0[3] : 0.f);
            f[4] = (__bf16)(valid ? (v[ks*8+4]-mu)*rs*w1[0]+b1[0] : 0.f);
            f[5] = (__bf16)(valid ? (v[ks*8+5]-mu)*rs*w1[1]+b1[1] : 0.f);
            f[6] = (__bf16)(valid ? (v[ks*8+6]-mu)*rs*w1[2]+b1[2] : 0.f);
            f[7] = (__bf16)(valid ? (v[ks*8+7]-mu)*rs*w1[3]+b1[3] : 0.f);
            afrag[mt][ks] = f;
        }
    }
    {
        const float qscale = 0.10206207261596577f; // 96^-0.5
        #pragma unroll 3
        for (int nt = 0; nt < 9; ++nt) {
            int j = ni*144 + nt*16 + rowm;          // output column (0..287)
            int wo = j*CC + quad*8;
            bf16x8 b0 = ldw8(qkv_w, qkv_wb, wo);
            bf16x8 b1 = ldw8(qkv_w, qkv_wb, wo + 32);
            bf16x8 b2 = ldw8(qkv_w, qkv_wb, wo + 64);
            float bias = qkv_b[j];
            #pragma unroll
            for (int mt = 0; mt < 2; ++mt) {
                f32x4 acc = (f32x4){0.f,0.f,0.f,0.f};
                acc = __builtin_amdgcn_mfma_f32_16x16x32_bf16(afrag[mt][0], b0, acc, 0,0,0);
                acc = __builtin_amdgcn_mfma_f32_16x16x32_bf16(afrag[mt][1], b1, acc, 0,0,0);
                acc = __builtin_amdgcn_mfma_f32_16x16x32_bf16(afrag[mt][2], b2, acc, 0,0,0);
                #pragma unroll
                for (int r = 0; r < 4; ++r) {
                    int tok = (2*mi+mt)*16 + quad*4 + r;
                    float val = acc[r] + bias;
                    if (j < 96)        qs [tok][j]      = (__bf16)(val * qscale);
                    else if (j < 192)  kss[tok][j-96]   = (__bf16)val;
                    else               vsT[j-192][tok]  = (__bf16)val;
                }
            }
        }
    }
    __syncthreads();

    // ---- phase 2: S = Q@K^T + rel_bias + mask; IN-REGISTER softmax; P->qs --
    {
        bf16x8 a0 = *(const bf16x8*)&qs[16*wv + rowm][ 0 + quad*8];
        bf16x8 a1 = *(const bf16x8*)&qs[16*wv + rowm][32 + quad*8];
        bf16x8 a2 = *(const bf16x8*)&qs[16*wv + rowm][64 + quad*8];
        f32x4 acc[4];
        int ky[4], kx[4];
        #pragma unroll
        for (int nt = 0; nt < 4; ++nt) {
            bf16x8 b0 = *(const bf16x8*)&kss[nt*16 + rowm][ 0 + quad*8];
            bf16x8 b1 = *(const bf16x8*)&kss[nt*16 + rowm][32 + quad*8];
            bf16x8 b2 = *(const bf16x8*)&kss[nt*16 + rowm][64 + quad*8];
            f32x4 t = (f32x4){0.f,0.f,0.f,0.f};
            t = __builtin_amdgcn_mfma_f32_16x16x32_bf16(a0, b0, t, 0,0,0);
            t = __builtin_amdgcn_mfma_f32_16x16x32_bf16(a1, b1, t, 0,0,0);
            t = __builtin_amdgcn_mfma_f32_16x16x32_bf16(a2, b2, t, 0,0,0);
            acc[nt] = t;
            int kt = nt*16 + rowm;
            ky[nt] = kt / 7; kx[nt] = kt - 7*ky[nt];
        }
        const bool eY = (wy == 31), eX = (wx == 31);
        #pragma unroll
        for (int r = 0; r < 4; ++r) {
            int qt = 16*wv + quad*4 + r;
            int qy = qt / 7, qx = qt - 7*qy;
            int lq = (eY ? (qy < 4 ? 3 : 6) : 0) + (eX ? (qx < 4 ? 1 : 2) : 0);
            float sv[4];
            #pragma unroll
            for (int nt = 0; nt < 4; ++nt) {
                int kt = nt*16 + rowm;
                float v = acc[nt][r];
                if (kt < TOK && qt < TOK) {
                    v += rel_table[(qy - ky[nt] + 6)*13 + (qx - kx[nt] + 6)];
                    if (eY || eX) {
                        int lk = (eY ? (ky[nt] < 4 ? 3 : 6) : 0)
                               + (eX ? (kx[nt] < 4 ? 1 : 2) : 0);
                        if (lq != lk) v -= 100.f;
                    }
                } else v = -3.0e38f;
                sv[nt] = v;
            }
            float m = fmaxf(fmaxf(sv[0], sv[1]), fmaxf(sv[2], sv[3]));
            #pragma unroll
            for (int off = 8; off; off >>= 1)
                m = fmaxf(m, __shfl_xor(m, off, 64));
            float e0 = __expf(sv[0]-m), e1 = __expf(sv[1]-m);
            float e2 = __expf(sv[2]-m), e3 = __expf(sv[3]-m);
            float s = (e0+e1)+(e2+e3);
            #pragma unroll
            for (int off = 8; off; off >>= 1)
                s += __shfl_xor(s, off, 64);
            float inv = 1.f / s;
            qs[qt][ 0 + rowm] = (__bf16)(e0*inv);
            qs[qt][16 + rowm] = (__bf16)(e1*inv);
            qs[qt][32 + rowm] = (__bf16)(e2*inv);
            qs[qt][48 + rowm] = (__bf16)(e3*inv);
        }
    }
    __syncthreads();

    // ---- phase 3: O = P @ V, MFMA; O -> kss (K dead) ----
    {
        bf16x8 a[2][2];
        #pragma unroll
        for (int mt = 0; mt < 2; ++mt)
            #pragma unroll
            for (int ku = 0; ku < 2; ++ku)
                a[mt][ku] = *(const bf16x8*)&qs[(2*mi+mt)*16 + rowm][ku*32 + quad*8];

        #pragma unroll
        for (int nt = 0; nt < 3; ++nt) {
            int c = ni*48 + nt*16 + rowm;
            bf16x8 b0 = *(const bf16x8*)&vsT[c][ 0 + quad*8];
            bf16x8 b1 = *(const bf16x8*)&vsT[c][32 + quad*8];
            #pragma unroll
            for (int mt = 0; mt < 2; ++mt) {
                f32x4 acc = (f32x4){0.f,0.f,0.f,0.f};
                acc = __builtin_amdgcn_mfma_f32_16x16x32_bf16(a[mt][0], b0, acc, 0,0,0);
                acc = __builtin_amdgcn_mfma_f32_16x16x32_bf16(a[mt][1], b1, acc, 0,0,0);
                #pragma unroll
                for (int r = 0; r < 4; ++r)
                    kss[(2*mi+mt)*16 + quad*4 + r][c] = (__bf16)acc[r];
            }
        }
    }
    __syncthreads();

    // ---- phase 4: out = O @ proj_w^T + bias + residual (addresses inline) --
    {
        bf16x8 a[2][3];
        #pragma unroll
        for (int mt = 0; mt < 2; ++mt)
            #pragma unroll
            for (int ks = 0; ks < 3; ++ks)
                a[mt][ks] = *(const bf16x8*)&kss[(2*mi+mt)*16 + rowm][ks*32 + quad*8];

        int obase[2][4];
        #pragma unroll
        for (int mt = 0; mt < 2; ++mt)
            #pragma unroll
            for (int r = 0; r < 4; ++r) {
                int tok = (2*mi+mt)*16 + quad*4 + r;
                if (tok < TOK) {
                    int ty = tok / 7, tx = tok - 7*ty;
                    int hr = wy*7 + ty, wr2 = wx*7 + tx;
                    int sh = hr + 3; if (sh >= HH) sh -= HH;
                    int sw = wr2 + 3; if (sw >= WW) sw -= WW;
                    obase[mt][r] = b*sB + sh*sH + sw*sW;
                } else obase[mt][r] = -1;
            }

        #pragma unroll
        for (int nt = 0; nt < 3; ++nt) {
            int c = ni*48 + nt*16 + rowm;
            int wo = c*CC + quad*8;
            bf16x8 b0 = ldw8(proj_w, proj_wb, wo);
            bf16x8 b1 = ldw8(proj_w, proj_wb, wo + 32);
            bf16x8 b2 = ldw8(proj_w, proj_wb, wo + 64);
            float bias = proj_b[c];
            #pragma unroll
            for (int mt = 0; mt < 2; ++mt) {
                f32x4 acc = (f32x4){0.f,0.f,0.f,0.f};
                acc = __builtin_amdgcn_mfma_f32_16x16x32_bf16(a[mt][0], b0, acc, 0,0,0);
                acc = __builtin_amdgcn_mfma_f32_16x16x32_bf16(a[mt][1], b1, acc, 0,0,0);
                acc = __builtin_amdgcn_mfma_f32_16x16x32_bf16(a[mt][2], b2, acc, 0,0,0);
                #pragma unroll
                for (int r = 0; r < 4; ++r) {
                    if (obase[mt][r] >= 0) {
                        int g = obase[mt][r] + c*sC;
                        outbuf[g] = inbuf[g] + acc[r] + bias;
                    }
                }
            }
        }
    }
}

// ---------------- Kernel B (fast path): LN2 + MLP + residual, MFMA --------
// 128 tokens/block (wave owns 32 = 2 row-sets): each weight fragment feeds
// 2 MFMAs; half the blocks; half the weight traffic per token.
// Register-fused LN2; B-fragments direct from global (bf16 cache);
// zero barriers in the chunk loop (sH wave-private).
// NCHW write-out fused via sOut overlay, staged in two 64-token passes.
// LDS = 24,832 B.
__global__ __launch_bounds__(256) void k_mlp_mfma(const float* __restrict__ buf,
                                                  float* __restrict__ out,
                                                  const float* __restrict__ n2w,
                                                  const float* __restrict__ n2b,
                                                  const float* __restrict__ w1g,
                                                  const float* __restrict__ b1g,
                                                  const float* __restrict__ w2g,
                                                  const float* __restrict__ b2g,
                                                  const __bf16* __restrict__ w1b,
                                                  const __bf16* __restrict__ w2b) {
    // sH [128][72] bf16 @0 (18432) ; epilogue overlay sOut [64][97] f32 (24832)
    __shared__ __attribute__((aligned(16))) char smraw[24832];
    auto sH   = (__bf16(*)[72])(smraw);
    auto sOut = (float(*)[97])(smraw);

    const int tid  = threadIdx.x;
    const int lane = tid & 63;
    const int wv   = tid >> 6;
    const int rowm = lane & 15;
    const int quad = lane >> 4;
    const int t0   = blockIdx.x * 128;

    // ---- fused LN2 in registers: wave owns tokens [32wv, 32wv+32) ----
    bf16x8 afrag[2][3];
    #pragma unroll
    for (int mt = 0; mt < 2; ++mt) {
        const int base = (t0 + 32*wv + mt*16 + rowm) * CC;
        float v[24];
        #pragma unroll
        for (int ks = 0; ks < 3; ++ks) {
            f32x4 x = *(const f32x4*)(buf + base + ks*32 + quad*8);
            f32x4 y = *(const f32x4*)(buf + base + ks*32 + quad*8 + 4);
            v[ks*8+0]=x[0]; v[ks*8+1]=x[1]; v[ks*8+2]=x[2]; v[ks*8+3]=x[3];
            v[ks*8+4]=y[0]; v[ks*8+5]=y[1]; v[ks*8+6]=y[2]; v[ks*8+7]=y[3];
        }
        float s = 0.f, s2 = 0.f;
        #pragma unroll
        for (int j = 0; j < 24; ++j) { s += v[j]; s2 += v[j]*v[j]; }
        s  += __shfl_xor(s,  16, 64);  s2 += __shfl_xor(s2, 16, 64);
        s  += __shfl_xor(s,  32, 64);  s2 += __shfl_xor(s2, 32, 64);
        float mu  = s * (1.f/96.f);
        float var = s2 * (1.f/96.f) - mu*mu;
        float rs  = rsqrtf(var + 1e-5f);
        #pragma unroll
        for (int ks = 0; ks < 3; ++ks) {
            int c0 = ks*32 + quad*8;
            f32x4 w0 = *(const f32x4*)(n2w + c0);
            f32x4 w1 = *(const f32x4*)(n2w + c0 + 4);
            f32x4 b0 = *(const f32x4*)(n2b + c0);
            f32x4 b1 = *(const f32x4*)(n2b + c0 + 4);
            bf16x8 f;
            f[0] = (__bf16)((v[ks*8+0]-mu)*rs*w0[0]+b0[0]);
            f[1] = (__bf16)((v[ks*8+1]-mu)*rs*w0[1]+b0[1]);
            f[2] = (__bf16)((v[ks*8+2]-mu)*rs*w0[2]+b0[2]);
            f[3] = (__bf16)((v[ks*8+3]-mu)*rs*w0[3]+b0[3]);
            f[4] = (__bf16)((v[ks*8+4]-mu)*rs*w1[0]+b1[0]);
            f[5] = (__bf16)((v[ks*8+5]-mu)*rs*w1[1]+b1[1]);
            f[6] = (__bf16)((v[ks*8+6]-mu)*rs*w1[2]+b1[2]);
            f[7] = (__bf16)((v[ks*8+7]-mu)*rs*w1[3]+b1[3]);
            afrag[mt][ks] = f;
        }
    }

    f32x4 acc2[2][6];
    #pragma unroll
    for (int mt = 0; mt < 2; ++mt)
        #pragma unroll
        for (int nt = 0; nt < 6; ++nt) acc2[mt][nt] = (f32x4){0.f,0.f,0.f,0.f};

    for (int ch = 0; ch < 6; ++ch) {
        // GEMM1 + GELU -> sH (wave-private rows; one weight load -> 2 MFMAs)
        #pragma unroll
        for (int nt = 0; nt < 4; ++nt) {
            int row = ch*64 + nt*16 + rowm;           // W1 row (hidden unit)
            int wo = row*96 + quad*8;
            bf16x8 w0  = ldw8(w1g, w1b, wo);
            bf16x8 w1v = ldw8(w1g, w1b, wo + 32);
            bf16x8 w2v = ldw8(w1g, w1b, wo + 64);
            float bias = b1g[row];
            #pragma unroll
            for (int mt = 0; mt < 2; ++mt) {
                f32x4 acc = (f32x4){0.f,0.f,0.f,0.f};
                acc = __builtin_amdgcn_mfma_f32_16x16x32_bf16(afrag[mt][0], w0,  acc, 0,0,0);
                acc = __builtin_amdgcn_mfma_f32_16x16x32_bf16(afrag[mt][1], w1v, acc, 0,0,0);
                acc = __builtin_amdgcn_mfma_f32_16x16x32_bf16(afrag[mt][2], w2v, acc, 0,0,0);
                #pragma unroll
                for (int r = 0; r < 4; ++r) {
                    float v = acc[r] + bias;
                    v = 0.5f * v * (1.f + erff(v * 0.70710678118654752f));
                    sH[32*wv + mt*16 + quad*4 + r][nt*16 + rowm] = (__bf16)v;
                }
            }
        }

        // GEMM2 partial: reads sH rows this wave just wrote (lgkmcnt-ordered)
        bf16x8 h0[2], h1[2];
        #pragma unroll
        for (int mt = 0; mt < 2; ++mt) {
            h0[mt] = *(const bf16x8*)&sH[32*wv + mt*16 + rowm][ 0 + quad*8];
            h1[mt] = *(const bf16x8*)&sH[32*wv + mt*16 + rowm][32 + quad*8];
        }
        #pragma unroll
        for (int nt = 0; nt < 6; ++nt) {
            int row = nt*16 + rowm;                    // W2 row (output channel)
            int wo = row*384 + ch*64 + quad*8;
            bf16x8 w0  = ldw8(w2g, w2b, wo);
            bf16x8 w1v = ldw8(w2g, w2b, wo + 32);
            #pragma unroll
            for (int mt = 0; mt < 2; ++mt) {
                acc2[mt][nt] = __builtin_amdgcn_mfma_f32_16x16x32_bf16(h0[mt], w0,  acc2[mt][nt], 0,0,0);
                acc2[mt][nt] = __builtin_amdgcn_mfma_f32_16x16x32_bf16(h1[mt], w1v, acc2[mt][nt], 0,0,0);
            }
        }
    }

    // ---- epilogue: + b2 + residual -> sOut (overlays sH), NCHW store -------
    // two 64-token passes through the same [64][97] staging buffer.
    const int b  = t0 / HWPIX;           // 128 | HWPIX, never straddles b
    const int p0 = t0 - b*HWPIX;
    __syncthreads();   // all waves done with sH before overlay write
    #pragma unroll
    for (int p = 0; p < 2; ++p) {
        if ((wv >> 1) == p) {            // waves 2p, 2p+1 own tokens [64p,64p+64)
            #pragma unroll
            for (int mt = 0; mt < 2; ++mt) {
                #pragma unroll
                for (int nt = 0; nt < 6; ++nt) {
                    int c = nt*16 + rowm;
                    float bias = b2g[c];
                    #pragma unroll
                    for (int r = 0; r < 4; ++r) {
                        int tl = 32*(wv & 1) + mt*16 + quad*4 + r;  // 0..63
                        sOut[tl][c] = buf[(t0 + 64*p + tl)*CC + c] + acc2[mt][nt][r] + bias;
                    }
                }
            }
        }
        __syncthreads();
        for (int i = tid; i < CC*64; i += 256) {
            int c = i >> 6, t = i & 63;
            out[(b*CC + c)*HWPIX + p0 + 64*p + t] = sOut[t][c];
        }
        if (p == 0) __syncthreads();     // before pass-1 overwrites sOut
    }
}

// ---------------- Kernel B (fallback, strided scalar) ----------------------
__global__ __launch_bounds__(256) void k_mlp_s(float* __restrict__ buf,
                                               const float* __restrict__ n2w,
                                               const float* __restrict__ n2b,
                                               const float* __restrict__ w1,
                                               const float* __restrict__ b1,
                                               const float* __restrict__ w2,
                                               const float* __restrict__ b2,
                                               int sB, int sPix, int sC) {
    __shared__ float ln2[4][CC];
    __shared__ float hid[4][384];
    __shared__ float hraw[4][CC];
    __shared__ int   tbase[4];

    const int tid  = threadIdx.x;
    const int lane = tid & 63;
    const int wv   = tid >> 6;
    const int tok0 = blockIdx.x * 4;

    {
        int tok = tok0 + wv;
        int base = (tok / HWPIX)*sB + (tok % HWPIX)*sPix;
        if (lane == 0) tbase[wv] = base;
        float v0 = buf[base + lane*sC];
        float v1 = (lane < 32) ? buf[base + (64 + lane)*sC] : 0.f;
        float s  = v0 + v1;
        float s2 = v0*v0 + v1*v1;
        #pragma unroll
        for (int off = 32; off; off >>= 1) {
            s  += __shfl_down(s,  off, 64);
            s2 += __shfl_down(s2, off, 64);
        }
        s  = __shfl(s, 0, 64);
        s2 = __shfl(s2, 0, 64);
        float mu  = s * (1.f/96.f);
        float var = s2 * (1.f/96.f) - mu*mu;
        float rs  = rsqrtf(var + 1e-5f);
        hraw[wv][lane] = v0;
        ln2[wv][lane]  = (v0 - mu)*rs*n2w[lane] + n2b[lane];
        if (lane < 32) {
            hraw[wv][64+lane] = v1;
            ln2[wv][64+lane]  = (v1 - mu)*rs*n2w[64+lane] + n2b[64+lane];
        }
    }
    __syncthreads();

    for (int o = tid; o < 4*384; o += 256) {
        int ti = o / 384, j = o % 384;
        const float* wrow = w1 + j*CC;
        float acc = b1[j];
        #pragma unroll 8
        for (int c = 0; c < CC; ++c) acc += ln2[ti][c] * wrow[c];
        hid[ti][j] = 0.5f * acc * (1.f + erff(acc * 0.70710678118654752f));
    }
    __syncthreads();

    for (int o = tid; o < 4*CC; o += 256) {
        int ti = o / CC, c = o % CC;
        const float* wrow = w2 + c*384;
        float acc = b2[c];
        #pragma unroll 8
        for (int k = 0; k < 384; ++k) acc += hid[ti][k] * wrow[k];
        buf[tbase[ti] + c*sC] = hraw[ti][c] + acc;
    }
}

extern "C" void kernel_launch(void* const* d_in, const int* in_sizes, int n_in,
                              void* d_out, int out_size, void* d_ws, size_t ws_size,
                              hipStream_t stream) {
    const float* x        = (const float*)d_in[0];
    const float* norm1_w  = (const float*)d_in[1];
    const float* norm1_b  = (const float*)d_in[2];
    const float* qkv_w    = (const float*)d_in[3];
    const float* qkv_b    = (const float*)d_in[4];
    const float* rel_tab  = (const float*)d_in[5];
    const float* proj_w   = (const float*)d_in[6];
    const float* proj_b   = (const float*)d_in[7];
    const float* norm2_w  = (const float*)d_in[8];
    const float* norm2_b  = (const float*)d_in[9];
    const float* mlp_w1   = (const float*)d_in[10];
    const float* mlp_b1   = (const float*)d_in[11];
    const float* mlp_w2   = (const float*)d_in[12];
    const float* mlp_b2   = (const float*)d_in[13];
    float* out = (float*)d_out;

    const int n = BB*CC*HH*WW;
    const size_t need = (size_t)n * sizeof(float); // 154,140,672 B

    dim3 blk(256);
    if (ws_size >= need) {
        float* hbuf = (float*)d_ws;
        __bf16* qkv_wb = nullptr; __bf16* proj_wb = nullptr;
        __bf16* w1b = nullptr;    __bf16* w2b = nullptr;
        if (ws_size >= need + WTAIL_BYTES) {
            __bf16* wt = (__bf16*)((char*)d_ws + need);
            qkv_wb  = wt;
            proj_wb = wt + 27648;
            w1b     = wt + 36864;
            w2b     = wt + 73728;
            k_cvt_all<<<dim3(54), blk, 0, stream>>>(qkv_w, proj_w, mlp_w1, mlp_w2, wt);
        }
        k_nchw2nhwc<<<dim3(BB*HH*4), blk, 0, stream>>>(x, hbuf);
        k_attn<<<dim3(BB*NWIN), blk, 0, stream>>>(hbuf, hbuf,
                norm1_w, norm1_b, qkv_w, qkv_b, rel_tab, proj_w, proj_b,
                qkv_wb, proj_wb,
                HH*WW*CC, WW*CC, CC, 1);
        k_mlp_mfma<<<dim3(NTOK/128), blk, 0, stream>>>(hbuf, out,
                norm2_w, norm2_b, mlp_w1, mlp_b1, mlp_w2, mlp_b2, w1b, w2b);
    } else {
        k_attn<<<dim3(BB*NWIN), blk, 0, stream>>>(x, out,
                norm1_w, norm1_b, qkv_w, qkv_b, rel_tab, proj_w, proj_b,
                nullptr, nullptr,
                CC*HH*WW, WW, 1, HH*WW);
        k_mlp_s<<<dim3(NTOK/4), blk, 0, stream>>>(out,
                norm2_w, norm2_b, mlp_w1, mlp_b1, mlp_w2, mlp_b2,
                CC*HH*WW, 1, HH*WW);
    }
}